// Round 1
// baseline (974.417 us; speedup 1.0000x reference)
//
#include <hip/hip_runtime.h>
#include <math.h>

#define N_NODES 50000
#define N_EDGES 800000
#define D 128
#define NH 8
#define HD 16
#define C3 384
#define EPS 1e-5f
#define QSCALE 0.08838834764831845f  // 128^-0.5

// ---------------------------------------------------------------------------
// helpers
// ---------------------------------------------------------------------------
__device__ __forceinline__ void atomicMaxFloat(float* addr, float val) {
    // standard bit-trick: int max for >=0, uint min for <0; init must be -inf
    if (val >= 0.f) atomicMax((int*)addr, __float_as_int(val));
    else            atomicMin((unsigned int*)addr, __float_as_uint(val));
}

// ---------------------------------------------------------------------------
// K0: init m = -inf, denom = 0, agg = 0
// ---------------------------------------------------------------------------
__global__ void k_init(float* __restrict__ m, float* __restrict__ denom,
                       float* __restrict__ agg) {
    int stride = gridDim.x * blockDim.x;
    int tid = blockIdx.x * blockDim.x + threadIdx.x;
    for (int i = tid; i < N_NODES * NH; i += stride) {
        m[i] = -INFINITY;
        denom[i] = 0.f;
    }
    for (int i = tid; i < N_NODES * D; i += stride) agg[i] = 0.f;
}

// ---------------------------------------------------------------------------
// K1: LayerNorm + QKV projection.
// Block: 256 threads, 64 nodes. GEMM: 4 col-tiles of 96, thread computes
// 8 nodes x 3 cols with float4 k-steps from LDS.
// ---------------------------------------------------------------------------
#define NT 64
#define CT 96
#define XP 132   // pitch (floats), keeps float4 alignment

__launch_bounds__(256)
__global__ void k_ln_qkv(const float* __restrict__ nf, const float* __restrict__ gamma,
                         const float* __restrict__ beta, const float* __restrict__ Wqkv,
                         const float* __restrict__ bqkv,
                         float* __restrict__ qb, float* __restrict__ kb,
                         float* __restrict__ vb) {
    __shared__ float xs[NT][XP];
    __shared__ float ws[CT][XP];
    const int tid = threadIdx.x;
    const int n0 = blockIdx.x * NT;

    // cooperative coalesced load of 64 node rows
    for (int i = tid; i < NT * (D / 4); i += 256) {
        int node = i >> 5, off = (i & 31) << 2;
        float4 w = make_float4(0.f, 0.f, 0.f, 0.f);
        if (n0 + node < N_NODES)
            w = *(const float4*)(nf + (size_t)(n0 + node) * D + off);
        *(float4*)&xs[node][off] = w;
    }
    __syncthreads();

    // LayerNorm: 4 threads per node
    {
        int node = tid >> 2, seg = tid & 3;
        float s = 0.f, ss = 0.f;
        #pragma unroll
        for (int j = 0; j < 32; j++) {
            float x = xs[node][seg * 32 + j];
            s += x; ss += x * x;
        }
        s += __shfl_xor(s, 1); ss += __shfl_xor(ss, 1);
        s += __shfl_xor(s, 2); ss += __shfl_xor(ss, 2);
        float mu = s * (1.f / 128.f);
        float var = ss * (1.f / 128.f) - mu * mu;
        float rstd = rsqrtf(var + EPS);
        #pragma unroll
        for (int j = 0; j < 32; j++) {
            int d = seg * 32 + j;
            float x = xs[node][d];
            xs[node][d] = (x - mu) * rstd * gamma[d] + beta[d];
        }
    }
    __syncthreads();

    const int tc = tid & 31, tn = tid >> 5;  // tn in [0,8): 8 nodes each

    for (int ct = 0; ct < 4; ct++) {
        // stage W tile rows [ct*96, ct*96+96)
        for (int i = tid; i < CT * 32; i += 256) {
            int r = i >> 5, off = (i & 31) << 2;
            *(float4*)&ws[r][off] =
                *(const float4*)(Wqkv + (size_t)(ct * CT + r) * D + off);
        }
        __syncthreads();

        float acc[8][3];
        #pragma unroll
        for (int a = 0; a < 8; a++)
            #pragma unroll
            for (int b = 0; b < 3; b++) acc[a][b] = 0.f;

        #pragma unroll 4
        for (int k4 = 0; k4 < 32; k4++) {
            float4 xv[8], wv[3];
            #pragma unroll
            for (int a = 0; a < 8; a++)
                xv[a] = *(const float4*)&xs[tn * 8 + a][k4 * 4];
            #pragma unroll
            for (int b = 0; b < 3; b++)
                wv[b] = *(const float4*)&ws[tc + 32 * b][k4 * 4];
            #pragma unroll
            for (int a = 0; a < 8; a++)
                #pragma unroll
                for (int b = 0; b < 3; b++) {
                    acc[a][b] += xv[a].x * wv[b].x + xv[a].y * wv[b].y +
                                 xv[a].z * wv[b].z + xv[a].w * wv[b].w;
                }
        }

        #pragma unroll
        for (int b = 0; b < 3; b++) {
            int c = ct * CT + tc + 32 * b;
            float bias = bqkv[c];
            #pragma unroll
            for (int a = 0; a < 8; a++) {
                int node = n0 + tn * 8 + a;
                if (node >= N_NODES) continue;
                float val = acc[a][b] + bias;
                if (c < 128)      qb[(size_t)node * D + c]         = val * QSCALE;
                else if (c < 256) kb[(size_t)node * D + (c - 128)] = val;
                else              vb[(size_t)node * D + (c - 256)] = val;
            }
        }
        __syncthreads();
    }
}

// ---------------------------------------------------------------------------
// K2: per-edge attention logits + segment max. One wave per edge.
// lane l covers dims l (heads 0-3) and l+64 (heads 4-7).
// ---------------------------------------------------------------------------
__global__ void k_edge_logits(const float* __restrict__ qb, const float* __restrict__ kb,
                              const float* __restrict__ dist, const float* __restrict__ path,
                              const int* __restrict__ src, const int* __restrict__ dst,
                              float* __restrict__ aex, float* __restrict__ m) {
    const int lane = threadIdx.x & 63;
    const int wave = blockIdx.x * (blockDim.x >> 6) + (threadIdx.x >> 6);
    const int nwaves = gridDim.x * (blockDim.x >> 6);
    for (int e = wave; e < N_EDGES; e += nwaves) {
        int s = src[e], d = dst[e];
        float p0 = qb[(size_t)s * D + lane]      * kb[(size_t)d * D + lane];
        float p1 = qb[(size_t)s * D + 64 + lane] * kb[(size_t)d * D + 64 + lane];
        #pragma unroll
        for (int off = 1; off < 16; off <<= 1) {
            p0 += __shfl_xor(p0, off);
            p1 += __shfl_xor(p1, off);
        }
        if ((lane & 15) == 0) {
            int h0 = lane >> 4, h1 = 4 + (lane >> 4);
            float a0 = p0 + dist[e * 8 + h0] + path[e * 8 + h0];
            float a1 = p1 + dist[e * 8 + h1] + path[e * 8 + h1];
            aex[e * 8 + h0] = a0;
            aex[e * 8 + h1] = a1;
            atomicMaxFloat(&m[d * 8 + h0], a0);
            atomicMaxFloat(&m[d * 8 + h1], a1);
        }
    }
}

// ---------------------------------------------------------------------------
// K3: ex = exp(a - m[dst]); denom[dst] += ex. One thread per (edge, head).
// ---------------------------------------------------------------------------
__global__ void k_exp_denom(const int* __restrict__ dst, const float* __restrict__ m,
                            float* __restrict__ aex, float* __restrict__ denom) {
    int stride = gridDim.x * blockDim.x;
    for (int i = blockIdx.x * blockDim.x + threadIdx.x; i < N_EDGES * NH; i += stride) {
        int e = i >> 3, h = i & 7;
        int d = dst[e];
        float ex = __expf(aex[i] - m[d * 8 + h]);
        aex[i] = ex;
        atomicAdd(&denom[d * 8 + h], ex);
    }
}

// ---------------------------------------------------------------------------
// K4: agg[dst] += v[src] * (ex / denom[dst]). One wave per edge.
// ---------------------------------------------------------------------------
__global__ void k_scatter(const float* __restrict__ vb, const float* __restrict__ aex,
                          const float* __restrict__ denom, const int* __restrict__ src,
                          const int* __restrict__ dst, float* __restrict__ agg) {
    const int lane = threadIdx.x & 63;
    const int wave = blockIdx.x * (blockDim.x >> 6) + (threadIdx.x >> 6);
    const int nwaves = gridDim.x * (blockDim.x >> 6);
    const int h0 = lane >> 4, h1 = 4 + (lane >> 4);
    for (int e = wave; e < N_EDGES; e += nwaves) {
        int s = src[e], d = dst[e];
        float sa0 = aex[e * 8 + h0] / denom[d * 8 + h0];
        float sa1 = aex[e * 8 + h1] / denom[d * 8 + h1];
        atomicAdd(&agg[(size_t)d * D + lane],      vb[(size_t)s * D + lane]      * sa0);
        atomicAdd(&agg[(size_t)d * D + 64 + lane], vb[(size_t)s * D + 64 + lane] * sa1);
    }
}

// ---------------------------------------------------------------------------
// K5: out = node_feature + agg @ W_out.T + b_out
// Block: 256 threads, 64 nodes; W_out fully staged in LDS.
// ---------------------------------------------------------------------------
__launch_bounds__(256)
__global__ void k_out(const float* __restrict__ agg, const float* __restrict__ Wout,
                      const float* __restrict__ bout, const float* __restrict__ nf,
                      float* __restrict__ out) {
    __shared__ float as[NT][XP];
    __shared__ float ws[128][XP];
    const int tid = threadIdx.x;
    const int n0 = blockIdx.x * NT;

    for (int i = tid; i < 128 * 32; i += 256) {
        int r = i >> 5, off = (i & 31) << 2;
        *(float4*)&ws[r][off] = *(const float4*)(Wout + (size_t)r * D + off);
    }
    for (int i = tid; i < NT * 32; i += 256) {
        int node = i >> 5, off = (i & 31) << 2;
        float4 w = make_float4(0.f, 0.f, 0.f, 0.f);
        if (n0 + node < N_NODES)
            w = *(const float4*)(agg + (size_t)(n0 + node) * D + off);
        *(float4*)&as[node][off] = w;
    }
    __syncthreads();

    const int tc = tid & 31, tn = tid >> 5;
    float acc[8][4];
    #pragma unroll
    for (int a = 0; a < 8; a++)
        #pragma unroll
        for (int b = 0; b < 4; b++) acc[a][b] = 0.f;

    #pragma unroll 4
    for (int k4 = 0; k4 < 32; k4++) {
        float4 av[8], wv[4];
        #pragma unroll
        for (int a = 0; a < 8; a++)
            av[a] = *(const float4*)&as[tn * 8 + a][k4 * 4];
        #pragma unroll
        for (int b = 0; b < 4; b++)
            wv[b] = *(const float4*)&ws[tc + 32 * b][k4 * 4];
        #pragma unroll
        for (int a = 0; a < 8; a++)
            #pragma unroll
            for (int b = 0; b < 4; b++) {
                acc[a][b] += av[a].x * wv[b].x + av[a].y * wv[b].y +
                             av[a].z * wv[b].z + av[a].w * wv[b].w;
            }
    }

    #pragma unroll
    for (int b = 0; b < 4; b++) {
        int c = tc + 32 * b;
        float bias = bout[c];
        #pragma unroll
        for (int a = 0; a < 8; a++) {
            int node = n0 + tn * 8 + a;
            if (node >= N_NODES) continue;
            out[(size_t)node * D + c] = nf[(size_t)node * D + c] + bias + acc[a][b];
        }
    }
}

// ---------------------------------------------------------------------------
// launch
// ---------------------------------------------------------------------------
extern "C" void kernel_launch(void* const* d_in, const int* in_sizes, int n_in,
                              void* d_out, int out_size, void* d_ws, size_t ws_size,
                              hipStream_t stream) {
    const float* nf    = (const float*)d_in[0];
    const float* dist  = (const float*)d_in[1];
    const float* path  = (const float*)d_in[2];
    const float* gamma = (const float*)d_in[3];
    const float* beta  = (const float*)d_in[4];
    const float* Wqkv  = (const float*)d_in[5];
    const float* bqkv  = (const float*)d_in[6];
    const float* Wout  = (const float*)d_in[7];
    const float* bout  = (const float*)d_in[8];
    const int*   src   = (const int*)d_in[9];
    const int*   dst   = (const int*)d_in[10];
    float* out = (float*)d_out;

    // workspace layout (floats)
    float* qb    = (float*)d_ws;                 // N*128
    float* kb    = qb + (size_t)N_NODES * D;     // N*128
    float* vb    = kb + (size_t)N_NODES * D;     // N*128
    float* aex   = vb + (size_t)N_NODES * D;     // E*8
    float* m     = aex + (size_t)N_EDGES * NH;   // N*8
    float* denom = m + (size_t)N_NODES * NH;     // N*8
    float* agg   = denom + (size_t)N_NODES * NH; // N*128

    (void)in_sizes; (void)n_in; (void)out_size; (void)ws_size;

    hipLaunchKernelGGL(k_init, dim3(2048), dim3(256), 0, stream, m, denom, agg);

    hipLaunchKernelGGL(k_ln_qkv, dim3((N_NODES + NT - 1) / NT), dim3(256), 0, stream,
                       nf, gamma, beta, Wqkv, bqkv, qb, kb, vb);

    hipLaunchKernelGGL(k_edge_logits, dim3(4096), dim3(256), 0, stream,
                       qb, kb, dist, path, src, dst, aex, m);

    hipLaunchKernelGGL(k_exp_denom, dim3(4096), dim3(256), 0, stream,
                       dst, m, aex, denom);

    hipLaunchKernelGGL(k_scatter, dim3(4096), dim3(256), 0, stream,
                       vb, aex, denom, src, dst, agg);

    hipLaunchKernelGGL(k_out, dim3((N_NODES + NT - 1) / NT), dim3(256), 0, stream,
                       agg, Wout, bout, nf, out);
}

// Round 2
// 927.376 us; speedup vs baseline: 1.0507x; 1.0507x over previous
//
#include <hip/hip_runtime.h>
#include <math.h>

#define N_NODES 50000
#define N_EDGES 800000
#define D 128
#define NH 8
#define HD 16
#define EPS 1e-5f
#define QSCALE 0.08838834764831845f  // 128^-0.5

#define NT 64
#define XP 132   // LDS pitch (floats), float4-aligned, breaks power-of-2 stride

// ---------------------------------------------------------------------------
// helpers
// ---------------------------------------------------------------------------
__device__ __forceinline__ void atomicMaxFloat(float* addr, float val) {
    if (val >= 0.f) atomicMax((int*)addr, __float_as_int(val));
    else            atomicMin((unsigned int*)addr, __float_as_uint(val));
}

// ---------------------------------------------------------------------------
// K0: init m = -inf, denom = 0, agg = 0
// ---------------------------------------------------------------------------
__global__ void k_init(float* __restrict__ m, float* __restrict__ denom,
                       float* __restrict__ agg) {
    int stride = gridDim.x * blockDim.x;
    int tid = blockIdx.x * blockDim.x + threadIdx.x;
    for (int i = tid; i < N_NODES * NH; i += stride) {
        m[i] = -INFINITY;
        denom[i] = 0.f;
    }
    for (int i = tid; i < N_NODES * D; i += stride) agg[i] = 0.f;
}

// ---------------------------------------------------------------------------
// K1: LayerNorm (register-resident) + QKV projection.
// 256 threads, 64 nodes/block. x staged in LDS (33.8KB -> 4 blocks/CU).
// W_qkv read directly from global: each lane streams 3 rows sequentially,
// L1-cached (196KB total, hot in L2 across blocks).
// ---------------------------------------------------------------------------
__launch_bounds__(256, 4)
__global__ void k_ln_qkv(const float* __restrict__ nf, const float* __restrict__ gamma,
                         const float* __restrict__ beta, const float* __restrict__ Wqkv,
                         const float* __restrict__ bqkv,
                         float* __restrict__ qb, float* __restrict__ kb,
                         float* __restrict__ vb) {
    __shared__ float xs[NT][XP];
    const int tid = threadIdx.x;
    const int n0 = blockIdx.x * NT;

    // ---- LayerNorm: 4 threads per node, fully in registers ----
    {
        const int node = tid >> 2, seg = tid & 3;
        const int gnode = n0 + node;
        float4 xr[8];
        if (gnode < N_NODES) {
            const float* row = nf + (size_t)gnode * D + seg * 32;
            #pragma unroll
            for (int j = 0; j < 8; j++) xr[j] = *(const float4*)(row + j * 4);
        } else {
            #pragma unroll
            for (int j = 0; j < 8; j++) xr[j] = make_float4(0.f, 0.f, 0.f, 0.f);
        }
        float s = 0.f, ss = 0.f;
        #pragma unroll
        for (int j = 0; j < 8; j++) {
            s  += xr[j].x + xr[j].y + xr[j].z + xr[j].w;
            ss += xr[j].x * xr[j].x + xr[j].y * xr[j].y +
                  xr[j].z * xr[j].z + xr[j].w * xr[j].w;
        }
        s += __shfl_xor(s, 1); ss += __shfl_xor(ss, 1);
        s += __shfl_xor(s, 2); ss += __shfl_xor(ss, 2);
        float mu = s * (1.f / 128.f);
        float var = ss * (1.f / 128.f) - mu * mu;
        float rstd = rsqrtf(var + EPS);
        #pragma unroll
        for (int j = 0; j < 8; j++) {
            float4 g  = *(const float4*)(gamma + seg * 32 + j * 4);
            float4 bt = *(const float4*)(beta  + seg * 32 + j * 4);
            float4 o;
            o.x = (xr[j].x - mu) * rstd * g.x + bt.x;
            o.y = (xr[j].y - mu) * rstd * g.y + bt.y;
            o.z = (xr[j].z - mu) * rstd * g.z + bt.z;
            o.w = (xr[j].w - mu) * rstd * g.w + bt.w;
            *(float4*)&xs[node][seg * 32 + j * 4] = o;
        }
    }
    __syncthreads();

    // ---- GEMM: thread = (tc, tn) -> 8 nodes x 3 cols per ct tile ----
    const int tc = tid & 31, tn = tid >> 5;

    for (int ct = 0; ct < 4; ct++) {
        const float* wr0 = Wqkv + (size_t)(ct * 96 + tc) * D;

        float acc[8][3];
        #pragma unroll
        for (int a = 0; a < 8; a++)
            #pragma unroll
            for (int b = 0; b < 3; b++) acc[a][b] = 0.f;

        #pragma unroll 4
        for (int k4 = 0; k4 < 32; k4++) {
            float4 wv[3];
            #pragma unroll
            for (int b = 0; b < 3; b++)
                wv[b] = *(const float4*)(wr0 + (size_t)b * 32 * D + k4 * 4);
            #pragma unroll
            for (int a = 0; a < 8; a++) {
                float4 xv = *(const float4*)&xs[tn * 8 + a][k4 * 4];
                #pragma unroll
                for (int b = 0; b < 3; b++) {
                    acc[a][b] += xv.x * wv[b].x + xv.y * wv[b].y +
                                 xv.z * wv[b].z + xv.w * wv[b].w;
                }
            }
        }

        #pragma unroll
        for (int b = 0; b < 3; b++) {
            int c = ct * 96 + tc + 32 * b;
            float bias = bqkv[c];
            #pragma unroll
            for (int a = 0; a < 8; a++) {
                int node = n0 + tn * 8 + a;
                if (node >= N_NODES) continue;
                float val = acc[a][b] + bias;
                if (c < 128)      qb[(size_t)node * D + c]         = val * QSCALE;
                else if (c < 256) kb[(size_t)node * D + (c - 128)] = val;
                else              vb[(size_t)node * D + (c - 256)] = val;
            }
        }
        // no barrier: xs is read-only from here on
    }
}

// ---------------------------------------------------------------------------
// K2: per-edge attention logits + segment max. One wave per edge.
// ---------------------------------------------------------------------------
__global__ void k_edge_logits(const float* __restrict__ qb, const float* __restrict__ kb,
                              const float* __restrict__ dist, const float* __restrict__ path,
                              const int* __restrict__ src, const int* __restrict__ dst,
                              float* __restrict__ aex, float* __restrict__ m) {
    const int lane = threadIdx.x & 63;
    const int wave = blockIdx.x * (blockDim.x >> 6) + (threadIdx.x >> 6);
    const int nwaves = gridDim.x * (blockDim.x >> 6);
    for (int e = wave; e < N_EDGES; e += nwaves) {
        int s = src[e], d = dst[e];
        float p0 = qb[(size_t)s * D + lane]      * kb[(size_t)d * D + lane];
        float p1 = qb[(size_t)s * D + 64 + lane] * kb[(size_t)d * D + 64 + lane];
        #pragma unroll
        for (int off = 1; off < 16; off <<= 1) {
            p0 += __shfl_xor(p0, off);
            p1 += __shfl_xor(p1, off);
        }
        if ((lane & 15) == 0) {
            int h0 = lane >> 4, h1 = 4 + (lane >> 4);
            float a0 = p0 + dist[e * 8 + h0] + path[e * 8 + h0];
            float a1 = p1 + dist[e * 8 + h1] + path[e * 8 + h1];
            aex[e * 8 + h0] = a0;
            aex[e * 8 + h1] = a1;
            atomicMaxFloat(&m[d * 8 + h0], a0);
            atomicMaxFloat(&m[d * 8 + h1], a1);
        }
    }
}

// ---------------------------------------------------------------------------
// K3: ex = exp(a - m[dst]); denom[dst] += ex. One thread per (edge, head).
// ---------------------------------------------------------------------------
__global__ void k_exp_denom(const int* __restrict__ dst, const float* __restrict__ m,
                            float* __restrict__ aex, float* __restrict__ denom) {
    int stride = gridDim.x * blockDim.x;
    for (int i = blockIdx.x * blockDim.x + threadIdx.x; i < N_EDGES * NH; i += stride) {
        int e = i >> 3, h = i & 7;
        int d = dst[e];
        float ex = __expf(aex[i] - m[d * 8 + h]);
        aex[i] = ex;
        atomicAdd(&denom[d * 8 + h], ex);
    }
}

// ---------------------------------------------------------------------------
// K4: agg[dst] += v[src] * (ex / denom[dst]). One wave per edge.
// ---------------------------------------------------------------------------
__global__ void k_scatter(const float* __restrict__ vb, const float* __restrict__ aex,
                          const float* __restrict__ denom, const int* __restrict__ src,
                          const int* __restrict__ dst, float* __restrict__ agg) {
    const int lane = threadIdx.x & 63;
    const int wave = blockIdx.x * (blockDim.x >> 6) + (threadIdx.x >> 6);
    const int nwaves = gridDim.x * (blockDim.x >> 6);
    const int h0 = lane >> 4, h1 = 4 + (lane >> 4);
    for (int e = wave; e < N_EDGES; e += nwaves) {
        int s = src[e], d = dst[e];
        float sa0 = aex[e * 8 + h0] / denom[d * 8 + h0];
        float sa1 = aex[e * 8 + h1] / denom[d * 8 + h1];
        atomicAdd(&agg[(size_t)d * D + lane],      vb[(size_t)s * D + lane]      * sa0);
        atomicAdd(&agg[(size_t)d * D + 64 + lane], vb[(size_t)s * D + 64 + lane] * sa1);
    }
}

// ---------------------------------------------------------------------------
// K5: out = node_feature + agg @ W_out.T + b_out
// Same structure as K1's GEMM: agg staged in LDS, W_out streamed from global.
// ---------------------------------------------------------------------------
__launch_bounds__(256, 4)
__global__ void k_out(const float* __restrict__ agg, const float* __restrict__ Wout,
                      const float* __restrict__ bout, const float* __restrict__ nf,
                      float* __restrict__ out) {
    __shared__ float as[NT][XP];
    const int tid = threadIdx.x;
    const int n0 = blockIdx.x * NT;

    for (int i = tid; i < NT * 32; i += 256) {
        int node = i >> 5, off = (i & 31) << 2;
        float4 w = make_float4(0.f, 0.f, 0.f, 0.f);
        if (n0 + node < N_NODES)
            w = *(const float4*)(agg + (size_t)(n0 + node) * D + off);
        *(float4*)&as[node][off] = w;
    }
    __syncthreads();

    const int tc = tid & 31, tn = tid >> 5;
    const float* wr0 = Wout + (size_t)tc * D;

    float acc[8][4];
    #pragma unroll
    for (int a = 0; a < 8; a++)
        #pragma unroll
        for (int b = 0; b < 4; b++) acc[a][b] = 0.f;

    #pragma unroll 4
    for (int k4 = 0; k4 < 32; k4++) {
        float4 wv[4];
        #pragma unroll
        for (int b = 0; b < 4; b++)
            wv[b] = *(const float4*)(wr0 + (size_t)b * 32 * D + k4 * 4);
        #pragma unroll
        for (int a = 0; a < 8; a++) {
            float4 av = *(const float4*)&as[tn * 8 + a][k4 * 4];
            #pragma unroll
            for (int b = 0; b < 4; b++) {
                acc[a][b] += av.x * wv[b].x + av.y * wv[b].y +
                             av.z * wv[b].z + av.w * wv[b].w;
            }
        }
    }

    #pragma unroll
    for (int b = 0; b < 4; b++) {
        int c = tc + 32 * b;
        float bias = bout[c];
        #pragma unroll
        for (int a = 0; a < 8; a++) {
            int node = n0 + tn * 8 + a;
            if (node >= N_NODES) continue;
            out[(size_t)node * D + c] = nf[(size_t)node * D + c] + bias + acc[a][b];
        }
    }
}

// ---------------------------------------------------------------------------
// launch
// ---------------------------------------------------------------------------
extern "C" void kernel_launch(void* const* d_in, const int* in_sizes, int n_in,
                              void* d_out, int out_size, void* d_ws, size_t ws_size,
                              hipStream_t stream) {
    const float* nf    = (const float*)d_in[0];
    const float* dist  = (const float*)d_in[1];
    const float* path  = (const float*)d_in[2];
    const float* gamma = (const float*)d_in[3];
    const float* beta  = (const float*)d_in[4];
    const float* Wqkv  = (const float*)d_in[5];
    const float* bqkv  = (const float*)d_in[6];
    const float* Wout  = (const float*)d_in[7];
    const float* bout  = (const float*)d_in[8];
    const int*   src   = (const int*)d_in[9];
    const int*   dst   = (const int*)d_in[10];
    float* out = (float*)d_out;

    // workspace layout (floats)
    float* qb    = (float*)d_ws;                 // N*128
    float* kb    = qb + (size_t)N_NODES * D;     // N*128
    float* vb    = kb + (size_t)N_NODES * D;     // N*128
    float* aex   = vb + (size_t)N_NODES * D;     // E*8
    float* m     = aex + (size_t)N_EDGES * NH;   // N*8
    float* denom = m + (size_t)N_NODES * NH;     // N*8
    float* agg   = denom + (size_t)N_NODES * NH; // N*128

    (void)in_sizes; (void)n_in; (void)out_size; (void)ws_size;

    hipLaunchKernelGGL(k_init, dim3(2048), dim3(256), 0, stream, m, denom, agg);

    hipLaunchKernelGGL(k_ln_qkv, dim3((N_NODES + NT - 1) / NT), dim3(256), 0, stream,
                       nf, gamma, beta, Wqkv, bqkv, qb, kb, vb);

    hipLaunchKernelGGL(k_edge_logits, dim3(4096), dim3(256), 0, stream,
                       qb, kb, dist, path, src, dst, aex, m);

    hipLaunchKernelGGL(k_exp_denom, dim3(4096), dim3(256), 0, stream,
                       dst, m, aex, denom);

    hipLaunchKernelGGL(k_scatter, dim3(4096), dim3(256), 0, stream,
                       vb, aex, denom, src, dst, agg);

    hipLaunchKernelGGL(k_out, dim3((N_NODES + NT - 1) / NT), dim3(256), 0, stream,
                       agg, Wout, bout, nf, out);
}

// Round 3
// 586.016 us; speedup vs baseline: 1.6628x; 1.5825x over previous
//
#include <hip/hip_runtime.h>
#include <math.h>

#define N_NODES 50000
#define N_EDGES 800000
#define D 128
#define NH 8
#define EPS 1e-5f
#define QSCALE 0.08838834764831845f  // 128^-0.5

// ---------------------------------------------------------------------------
// CSR build: zero -> histogram -> scan -> fill
// ---------------------------------------------------------------------------
__global__ void k_zero(int* __restrict__ cnt) {
    int i = blockIdx.x * blockDim.x + threadIdx.x;
    if (i < N_NODES) cnt[i] = 0;
}

__global__ void k_hist(const int* __restrict__ dst, int* __restrict__ cnt) {
    int e = blockIdx.x * blockDim.x + threadIdx.x;
    if (e < N_EDGES) atomicAdd(&cnt[dst[e]], 1);
}

#define SCAN_T 1024
#define SCAN_CH ((N_NODES + SCAN_T - 1) / SCAN_T)
__global__ void k_scan(const int* __restrict__ cnt, int* __restrict__ row_start,
                       int* __restrict__ ptrs) {
    __shared__ int ts[SCAN_T];
    const int tid = threadIdx.x;
    const int base = tid * SCAN_CH;
    int local = 0;
    #pragma unroll 4
    for (int i = 0; i < SCAN_CH; i++) {
        int idx = base + i;
        if (idx < N_NODES) local += cnt[idx];
    }
    ts[tid] = local;
    __syncthreads();
    // Hillis-Steele inclusive scan (read / barrier / write / barrier)
    for (int off = 1; off < SCAN_T; off <<= 1) {
        int v = (tid >= off) ? ts[tid - off] : 0;
        __syncthreads();
        ts[tid] += v;
        __syncthreads();
    }
    int run = (tid == 0) ? 0 : ts[tid - 1];
    for (int i = 0; i < SCAN_CH; i++) {
        int idx = base + i;
        if (idx < N_NODES) {
            int c = cnt[idx];          // read BEFORE any write (no-alias safe)
            row_start[idx] = run;
            ptrs[idx] = run;
            run += c;
        }
    }
    if (tid == SCAN_T - 1) row_start[N_NODES] = run;  // == N_EDGES
}

__global__ void k_fill(const int* __restrict__ src, const int* __restrict__ dst,
                       int* __restrict__ ptrs, int* __restrict__ ssrc,
                       int* __restrict__ eidx) {
    int e = blockIdx.x * blockDim.x + threadIdx.x;
    if (e < N_EDGES) {
        int d = dst[e];
        int pos = atomicAdd(&ptrs[d], 1);
        ssrc[pos] = src[e];
        eidx[pos] = e;
    }
}

// ---------------------------------------------------------------------------
// K1: LayerNorm + QKV projection.
// 256 threads, 32 nodes/block. xs[32][132]=16.9KB + ws[96][130]=49.9KB
// = 66.8KB -> 2 blocks/CU. ws read as float2 @ pitch 130:
// bank = (2r + 2k + j) % 32 -> 2 lanes/bank = free (m136).
// ---------------------------------------------------------------------------
__launch_bounds__(256)
__global__ void k_ln_qkv(const float* __restrict__ nf, const float* __restrict__ gamma,
                         const float* __restrict__ beta, const float* __restrict__ Wqkv,
                         const float* __restrict__ bqkv,
                         float* __restrict__ qb, float* __restrict__ kb,
                         float* __restrict__ vb) {
    __shared__ float xs[32][132];
    __shared__ float ws[96][130];
    const int tid = threadIdx.x;
    const int n0 = blockIdx.x * 32;

    // ---- LayerNorm: 8 threads/node, register-resident ----
    {
        const int node = tid >> 3, seg = tid & 7;
        const int gnode = n0 + node;
        float4 xr[4];
        if (gnode < N_NODES) {
            const float* row = nf + (size_t)gnode * D + seg * 16;
            #pragma unroll
            for (int j = 0; j < 4; j++) xr[j] = *(const float4*)(row + j * 4);
        } else {
            #pragma unroll
            for (int j = 0; j < 4; j++) xr[j] = make_float4(0.f, 0.f, 0.f, 0.f);
        }
        float s = 0.f, ss = 0.f;
        #pragma unroll
        for (int j = 0; j < 4; j++) {
            s  += xr[j].x + xr[j].y + xr[j].z + xr[j].w;
            ss += xr[j].x * xr[j].x + xr[j].y * xr[j].y +
                  xr[j].z * xr[j].z + xr[j].w * xr[j].w;
        }
        s += __shfl_xor(s, 1); ss += __shfl_xor(ss, 1);
        s += __shfl_xor(s, 2); ss += __shfl_xor(ss, 2);
        s += __shfl_xor(s, 4); ss += __shfl_xor(ss, 4);
        float mu = s * (1.f / 128.f);
        float var = ss * (1.f / 128.f) - mu * mu;
        float rstd = rsqrtf(var + EPS);
        #pragma unroll
        for (int j = 0; j < 4; j++) {
            float4 g  = *(const float4*)(gamma + seg * 16 + j * 4);
            float4 bt = *(const float4*)(beta  + seg * 16 + j * 4);
            float4 o;
            o.x = (xr[j].x - mu) * rstd * g.x + bt.x;
            o.y = (xr[j].y - mu) * rstd * g.y + bt.y;
            o.z = (xr[j].z - mu) * rstd * g.z + bt.z;
            o.w = (xr[j].w - mu) * rstd * g.w + bt.w;
            *(float4*)&xs[node][seg * 16 + j * 4] = o;
        }
    }
    __syncthreads();

    const int tc = tid & 31, tn = tid >> 5;   // tn in [0,8): nodes tn*4..tn*4+3

    for (int ct = 0; ct < 4; ct++) {
        if (ct) __syncthreads();              // prev reads done before restage
        for (int i = tid; i < 96 * 32; i += 256) {
            int r = i >> 5, off = (i & 31) << 2;
            float4 w = *(const float4*)(Wqkv + (size_t)(ct * 96 + r) * D + off);
            *(float2*)&ws[r][off]     = make_float2(w.x, w.y);
            *(float2*)&ws[r][off + 2] = make_float2(w.z, w.w);
        }
        __syncthreads();

        float acc[4][3];
        #pragma unroll
        for (int a = 0; a < 4; a++)
            #pragma unroll
            for (int b = 0; b < 3; b++) acc[a][b] = 0.f;

        #pragma unroll 2
        for (int k4 = 0; k4 < 32; k4++) {
            float2 wa[3], wb[3];
            #pragma unroll
            for (int b = 0; b < 3; b++) {
                wa[b] = *(const float2*)&ws[tc + 32 * b][k4 * 4];
                wb[b] = *(const float2*)&ws[tc + 32 * b][k4 * 4 + 2];
            }
            #pragma unroll
            for (int a = 0; a < 4; a++) {
                float4 xv = *(const float4*)&xs[tn * 4 + a][k4 * 4];  // broadcast
                #pragma unroll
                for (int b = 0; b < 3; b++) {
                    acc[a][b] += xv.x * wa[b].x + xv.y * wa[b].y +
                                 xv.z * wb[b].x + xv.w * wb[b].y;
                }
            }
        }

        #pragma unroll
        for (int b = 0; b < 3; b++) {
            int c = ct * 96 + tc + 32 * b;    // whole 32-range within one of q/k/v
            float bias = bqkv[c];
            #pragma unroll
            for (int a = 0; a < 4; a++) {
                int node = n0 + tn * 4 + a;
                if (node >= N_NODES) continue;
                float val = acc[a][b] + bias;
                if (c < 128)      qb[(size_t)node * D + c]         = val * QSCALE;
                else if (c < 256) kb[(size_t)node * D + (c - 128)] = val;
                else              vb[(size_t)node * D + (c - 256)] = val;
            }
        }
    }
}

// ---------------------------------------------------------------------------
// K_gather: fused logits + online softmax + weighted-V aggregation.
// One wave per node. Lane l owns dims (2l,2l+1) -> head h = l>>3 (uniform
// per 8-lane group). K-row register-resident; q/v gathered per edge as
// float2 (one coalesced 512B tx per row); 3x shfl_xor head reduce;
// flash-style online rescale. No atomics; agg written exactly once.
// ---------------------------------------------------------------------------
__launch_bounds__(256, 4)
__global__ void k_gather(const float* __restrict__ qb, const float* __restrict__ kb,
                         const float* __restrict__ vb, const float* __restrict__ dist,
                         const float* __restrict__ path,
                         const int* __restrict__ row_start, const int* __restrict__ ssrc,
                         const int* __restrict__ eidx, float* __restrict__ agg) {
    const int node = blockIdx.x * 4 + (threadIdx.x >> 6);
    if (node >= N_NODES) return;
    const int lane = threadIdx.x & 63;
    const int h = lane >> 3;
    const int beg = row_start[node], end = row_start[node + 1];

    const float2 kv = *(const float2*)(kb + (size_t)node * D + 2 * lane);
    float m = -INFINITY, sden = 0.f, ax = 0.f, ay = 0.f;

    int i = beg;
    for (; i + 2 <= end; i += 2) {          // 2-deep pipeline: batch the loads
        int sA = ssrc[i],  sB = ssrc[i + 1];
        int eA = eidx[i],  eB = eidx[i + 1];
        float2 qA = *(const float2*)(qb + (size_t)sA * D + 2 * lane);
        float2 qB = *(const float2*)(qb + (size_t)sB * D + 2 * lane);
        float2 vA = *(const float2*)(vb + (size_t)sA * D + 2 * lane);
        float2 vB = *(const float2*)(vb + (size_t)sB * D + 2 * lane);
        float dpA = dist[eA * 8 + h] + path[eA * 8 + h];
        float dpB = dist[eB * 8 + h] + path[eB * 8 + h];
        float pA = qA.x * kv.x + qA.y * kv.y;
        float pB = qB.x * kv.x + qB.y * kv.y;
        pA += __shfl_xor(pA, 1); pA += __shfl_xor(pA, 2); pA += __shfl_xor(pA, 4);
        pB += __shfl_xor(pB, 1); pB += __shfl_xor(pB, 2); pB += __shfl_xor(pB, 4);
        pA += dpA; pB += dpB;

        float mn = fmaxf(m, pA);
        float c  = __expf(m - mn);
        float w  = __expf(pA - mn);
        sden = sden * c + w;
        ax = ax * c + w * vA.x;
        ay = ay * c + w * vA.y;
        m = mn;

        mn = fmaxf(m, pB);
        c  = __expf(m - mn);
        w  = __expf(pB - mn);
        sden = sden * c + w;
        ax = ax * c + w * vB.x;
        ay = ay * c + w * vB.y;
        m = mn;
    }
    if (i < end) {                           // tail edge
        int sA = ssrc[i];
        int eA = eidx[i];
        float2 qA = *(const float2*)(qb + (size_t)sA * D + 2 * lane);
        float2 vA = *(const float2*)(vb + (size_t)sA * D + 2 * lane);
        float dpA = dist[eA * 8 + h] + path[eA * 8 + h];
        float pA = qA.x * kv.x + qA.y * kv.y;
        pA += __shfl_xor(pA, 1); pA += __shfl_xor(pA, 2); pA += __shfl_xor(pA, 4);
        pA += dpA;
        float mn = fmaxf(m, pA);
        float c  = __expf(m - mn);
        float w  = __expf(pA - mn);
        sden = sden * c + w;
        ax = ax * c + w * vA.x;
        ay = ay * c + w * vA.y;
    }

    float2 r = make_float2(0.f, 0.f);
    if (end > beg) {
        float inv = 1.f / sden;
        r = make_float2(ax * inv, ay * inv);
    }
    *(float2*)(agg + (size_t)node * D + 2 * lane) = r;
}

// ---------------------------------------------------------------------------
// K5: out = node_feature + agg @ W_out.T + b_out
// 64 nodes/block, 2 col-tiles of 64. as[64][132]+ws[64][130] = 67KB
// -> 2 blocks/CU. Conflict-free float2 W reads as in K1.
// ---------------------------------------------------------------------------
__launch_bounds__(256)
__global__ void k_out(const float* __restrict__ agg, const float* __restrict__ Wout,
                      const float* __restrict__ bout, const float* __restrict__ nf,
                      float* __restrict__ out) {
    __shared__ float as_[64][132];
    __shared__ float ws[64][130];
    const int tid = threadIdx.x;
    const int n0 = blockIdx.x * 64;

    for (int i = tid; i < 64 * 32; i += 256) {
        int node = i >> 5, off = (i & 31) << 2;
        float4 w = make_float4(0.f, 0.f, 0.f, 0.f);
        if (n0 + node < N_NODES)
            w = *(const float4*)(agg + (size_t)(n0 + node) * D + off);
        *(float4*)&as_[node][off] = w;
    }

    const int tc = tid & 31, tn = tid >> 5;   // nodes tn*8..tn*8+7

    for (int ct = 0; ct < 2; ct++) {
        if (ct) __syncthreads();
        for (int i = tid; i < 64 * 32; i += 256) {
            int r = i >> 5, off = (i & 31) << 2;
            float4 w = *(const float4*)(Wout + (size_t)(ct * 64 + r) * D + off);
            *(float2*)&ws[r][off]     = make_float2(w.x, w.y);
            *(float2*)&ws[r][off + 2] = make_float2(w.z, w.w);
        }
        __syncthreads();   // also covers as_ staging on ct==0

        float acc[8][2];
        #pragma unroll
        for (int a = 0; a < 8; a++)
            #pragma unroll
            for (int b = 0; b < 2; b++) acc[a][b] = 0.f;

        #pragma unroll 2
        for (int k4 = 0; k4 < 32; k4++) {
            float2 wa[2], wb[2];
            #pragma unroll
            for (int b = 0; b < 2; b++) {
                wa[b] = *(const float2*)&ws[tc + 32 * b][k4 * 4];
                wb[b] = *(const float2*)&ws[tc + 32 * b][k4 * 4 + 2];
            }
            #pragma unroll
            for (int a = 0; a < 8; a++) {
                float4 xv = *(const float4*)&as_[tn * 8 + a][k4 * 4];  // broadcast
                #pragma unroll
                for (int b = 0; b < 2; b++) {
                    acc[a][b] += xv.x * wa[b].x + xv.y * wa[b].y +
                                 xv.z * wb[b].x + xv.w * wb[b].y;
                }
            }
        }

        #pragma unroll
        for (int b = 0; b < 2; b++) {
            int c = ct * 64 + tc + 32 * b;
            float bias = bout[c];
            #pragma unroll
            for (int a = 0; a < 8; a++) {
                int node = n0 + tn * 8 + a;
                if (node >= N_NODES) continue;
                out[(size_t)node * D + c] = nf[(size_t)node * D + c] + bias + acc[a][b];
            }
        }
    }
}

// ---------------------------------------------------------------------------
// launch
// ---------------------------------------------------------------------------
extern "C" void kernel_launch(void* const* d_in, const int* in_sizes, int n_in,
                              void* d_out, int out_size, void* d_ws, size_t ws_size,
                              hipStream_t stream) {
    const float* nf    = (const float*)d_in[0];
    const float* dist  = (const float*)d_in[1];
    const float* path  = (const float*)d_in[2];
    const float* gamma = (const float*)d_in[3];
    const float* beta  = (const float*)d_in[4];
    const float* Wqkv  = (const float*)d_in[5];
    const float* bqkv  = (const float*)d_in[6];
    const float* Wout  = (const float*)d_in[7];
    const float* bout  = (const float*)d_in[8];
    const int*   src   = (const int*)d_in[9];
    const int*   dst   = (const int*)d_in[10];
    float* out = (float*)d_out;

    // workspace layout: 4 x N*128 floats + CSR ints (~109.5 MB total)
    float* qb  = (float*)d_ws;
    float* kb  = qb + (size_t)N_NODES * D;
    float* vb  = kb + (size_t)N_NODES * D;
    float* agg = vb + (size_t)N_NODES * D;
    int* ssrc      = (int*)(agg + (size_t)N_NODES * D);   // N_EDGES
    int* eidx      = ssrc + N_EDGES;                      // N_EDGES
    int* cnt       = eidx + N_EDGES;                      // N_NODES
    int* ptrs      = cnt + N_NODES;                       // N_NODES
    int* row_start = ptrs + N_NODES;                      // N_NODES + 1

    (void)in_sizes; (void)n_in; (void)out_size; (void)ws_size;

    hipLaunchKernelGGL(k_zero, dim3((N_NODES + 255) / 256), dim3(256), 0, stream, cnt);
    hipLaunchKernelGGL(k_hist, dim3((N_EDGES + 255) / 256), dim3(256), 0, stream,
                       dst, cnt);
    hipLaunchKernelGGL(k_scan, dim3(1), dim3(SCAN_T), 0, stream,
                       cnt, row_start, ptrs);
    hipLaunchKernelGGL(k_fill, dim3((N_EDGES + 255) / 256), dim3(256), 0, stream,
                       src, dst, ptrs, ssrc, eidx);

    hipLaunchKernelGGL(k_ln_qkv, dim3((N_NODES + 31) / 32), dim3(256), 0, stream,
                       nf, gamma, beta, Wqkv, bqkv, qb, kb, vb);

    hipLaunchKernelGGL(k_gather, dim3((N_NODES + 3) / 4), dim3(256), 0, stream,
                       qb, kb, vb, dist, path, row_start, ssrc, eidx, agg);

    hipLaunchKernelGGL(k_out, dim3((N_NODES + 63) / 64), dim3(256), 0, stream,
                       agg, Wout, bout, nf, out);
}

// Round 4
// 582.616 us; speedup vs baseline: 1.6725x; 1.0058x over previous
//
#include <hip/hip_runtime.h>
#include <math.h>

#define N_NODES 50000
#define N_EDGES 800000
#define D 128
#define NH 8
#define EPS 1e-5f
#define QSCALE 0.08838834764831845f  // 128^-0.5

// ---------------------------------------------------------------------------
// CSR build: zero -> histogram -> scan -> fill
// ---------------------------------------------------------------------------
__global__ void k_zero(int* __restrict__ cnt) {
    int i = blockIdx.x * blockDim.x + threadIdx.x;
    if (i < N_NODES) cnt[i] = 0;
}

__global__ void k_hist(const int* __restrict__ dst, int* __restrict__ cnt) {
    int e = blockIdx.x * blockDim.x + threadIdx.x;
    if (e < N_EDGES) atomicAdd(&cnt[dst[e]], 1);
}

#define SCAN_T 1024
#define SCAN_CH ((N_NODES + SCAN_T - 1) / SCAN_T)
__global__ void k_scan(const int* __restrict__ cnt, int* __restrict__ row_start,
                       int* __restrict__ ptrs) {
    __shared__ int ts[SCAN_T];
    const int tid = threadIdx.x;
    const int base = tid * SCAN_CH;
    int local = 0;
    #pragma unroll 4
    for (int i = 0; i < SCAN_CH; i++) {
        int idx = base + i;
        if (idx < N_NODES) local += cnt[idx];
    }
    ts[tid] = local;
    __syncthreads();
    // Hillis-Steele inclusive scan (read / barrier / write / barrier)
    for (int off = 1; off < SCAN_T; off <<= 1) {
        int v = (tid >= off) ? ts[tid - off] : 0;
        __syncthreads();
        ts[tid] += v;
        __syncthreads();
    }
    int run = (tid == 0) ? 0 : ts[tid - 1];
    for (int i = 0; i < SCAN_CH; i++) {
        int idx = base + i;
        if (idx < N_NODES) {
            int c = cnt[idx];          // read BEFORE any write (no-alias safe)
            row_start[idx] = run;
            ptrs[idx] = run;
            run += c;
        }
    }
    if (tid == SCAN_T - 1) row_start[N_NODES] = run;  // == N_EDGES
}

__global__ void k_fill(const int* __restrict__ src, const int* __restrict__ dst,
                       int* __restrict__ ptrs, int* __restrict__ ssrc,
                       int* __restrict__ eidx) {
    int e = blockIdx.x * blockDim.x + threadIdx.x;
    if (e < N_EDGES) {
        int d = dst[e];
        int pos = atomicAdd(&ptrs[d], 1);
        ssrc[pos] = src[e];
        eidx[pos] = e;
    }
}

// ---------------------------------------------------------------------------
// K1: LayerNorm + QKV projection.
// 256 threads, 32 nodes/block. xs[32][132]=16.9KB + ws[96][130]=49.9KB
// = 66.8KB -> 2 blocks/CU. ws read as float2 @ pitch 130:
// bank = (2r + 2k + j) % 32 -> 2 lanes/bank = free (m136).
// ---------------------------------------------------------------------------
__launch_bounds__(256)
__global__ void k_ln_qkv(const float* __restrict__ nf, const float* __restrict__ gamma,
                         const float* __restrict__ beta, const float* __restrict__ Wqkv,
                         const float* __restrict__ bqkv,
                         float* __restrict__ qb, float* __restrict__ kb,
                         float* __restrict__ vb) {
    __shared__ float xs[32][132];
    __shared__ float ws[96][130];
    const int tid = threadIdx.x;
    const int n0 = blockIdx.x * 32;

    // ---- LayerNorm: 8 threads/node, register-resident ----
    {
        const int node = tid >> 3, seg = tid & 7;
        const int gnode = n0 + node;
        float4 xr[4];
        if (gnode < N_NODES) {
            const float* row = nf + (size_t)gnode * D + seg * 16;
            #pragma unroll
            for (int j = 0; j < 4; j++) xr[j] = *(const float4*)(row + j * 4);
        } else {
            #pragma unroll
            for (int j = 0; j < 4; j++) xr[j] = make_float4(0.f, 0.f, 0.f, 0.f);
        }
        float s = 0.f, ss = 0.f;
        #pragma unroll
        for (int j = 0; j < 4; j++) {
            s  += xr[j].x + xr[j].y + xr[j].z + xr[j].w;
            ss += xr[j].x * xr[j].x + xr[j].y * xr[j].y +
                  xr[j].z * xr[j].z + xr[j].w * xr[j].w;
        }
        s += __shfl_xor(s, 1); ss += __shfl_xor(ss, 1);
        s += __shfl_xor(s, 2); ss += __shfl_xor(ss, 2);
        s += __shfl_xor(s, 4); ss += __shfl_xor(ss, 4);
        float mu = s * (1.f / 128.f);
        float var = ss * (1.f / 128.f) - mu * mu;
        float rstd = rsqrtf(var + EPS);
        #pragma unroll
        for (int j = 0; j < 4; j++) {
            float4 g  = *(const float4*)(gamma + seg * 16 + j * 4);
            float4 bt = *(const float4*)(beta  + seg * 16 + j * 4);
            float4 o;
            o.x = (xr[j].x - mu) * rstd * g.x + bt.x;
            o.y = (xr[j].y - mu) * rstd * g.y + bt.y;
            o.z = (xr[j].z - mu) * rstd * g.z + bt.z;
            o.w = (xr[j].w - mu) * rstd * g.w + bt.w;
            *(float4*)&xs[node][seg * 16 + j * 4] = o;
        }
    }
    __syncthreads();

    const int tc = tid & 31, tn = tid >> 5;   // tn in [0,8): nodes tn*4..tn*4+3

    for (int ct = 0; ct < 4; ct++) {
        if (ct) __syncthreads();              // prev reads done before restage
        for (int i = tid; i < 96 * 32; i += 256) {
            int r = i >> 5, off = (i & 31) << 2;
            float4 w = *(const float4*)(Wqkv + (size_t)(ct * 96 + r) * D + off);
            *(float2*)&ws[r][off]     = make_float2(w.x, w.y);
            *(float2*)&ws[r][off + 2] = make_float2(w.z, w.w);
        }
        __syncthreads();

        float acc[4][3];
        #pragma unroll
        for (int a = 0; a < 4; a++)
            #pragma unroll
            for (int b = 0; b < 3; b++) acc[a][b] = 0.f;

        #pragma unroll 2
        for (int k4 = 0; k4 < 32; k4++) {
            float2 wa[3], wb[3];
            #pragma unroll
            for (int b = 0; b < 3; b++) {
                wa[b] = *(const float2*)&ws[tc + 32 * b][k4 * 4];
                wb[b] = *(const float2*)&ws[tc + 32 * b][k4 * 4 + 2];
            }
            #pragma unroll
            for (int a = 0; a < 4; a++) {
                float4 xv = *(const float4*)&xs[tn * 4 + a][k4 * 4];  // broadcast
                #pragma unroll
                for (int b = 0; b < 3; b++) {
                    acc[a][b] += xv.x * wa[b].x + xv.y * wa[b].y +
                                 xv.z * wb[b].x + xv.w * wb[b].y;
                }
            }
        }

        #pragma unroll
        for (int b = 0; b < 3; b++) {
            int c = ct * 96 + tc + 32 * b;    // whole 32-range within one of q/k/v
            float bias = bqkv[c];
            #pragma unroll
            for (int a = 0; a < 4; a++) {
                int node = n0 + tn * 4 + a;
                if (node >= N_NODES) continue;
                float val = acc[a][b] + bias;
                if (c < 128)      qb[(size_t)node * D + c]         = val * QSCALE;
                else if (c < 256) kb[(size_t)node * D + (c - 128)] = val;
                else              vb[(size_t)node * D + (c - 256)] = val;
            }
        }
    }
}

// ---------------------------------------------------------------------------
// K_gather: fused logits + online softmax + weighted-V aggregation.
// One wave per node. Lane l owns dims (2l,2l+1) -> head h = l>>3 (uniform
// per 8-lane group). K-row register-resident; q/v gathered per edge as
// float2 (one coalesced 512B tx per row); 3x shfl_xor head reduce;
// flash-style online rescale. No atomics; agg written exactly once.
// ---------------------------------------------------------------------------
__launch_bounds__(256, 4)
__global__ void k_gather(const float* __restrict__ qb, const float* __restrict__ kb,
                         const float* __restrict__ vb, const float* __restrict__ dist,
                         const float* __restrict__ path,
                         const int* __restrict__ row_start, const int* __restrict__ ssrc,
                         const int* __restrict__ eidx, float* __restrict__ agg) {
    const int node = blockIdx.x * 4 + (threadIdx.x >> 6);
    if (node >= N_NODES) return;
    const int lane = threadIdx.x & 63;
    const int h = lane >> 3;
    const int beg = row_start[node], end = row_start[node + 1];

    const float2 kv = *(const float2*)(kb + (size_t)node * D + 2 * lane);
    float m = -INFINITY, sden = 0.f, ax = 0.f, ay = 0.f;

    int i = beg;
    for (; i + 2 <= end; i += 2) {          // 2-deep pipeline: batch the loads
        int sA = ssrc[i],  sB = ssrc[i + 1];
        int eA = eidx[i],  eB = eidx[i + 1];
        float2 qA = *(const float2*)(qb + (size_t)sA * D + 2 * lane);
        float2 qB = *(const float2*)(qb + (size_t)sB * D + 2 * lane);
        float2 vA = *(const float2*)(vb + (size_t)sA * D + 2 * lane);
        float2 vB = *(const float2*)(vb + (size_t)sB * D + 2 * lane);
        float dpA = dist[eA * 8 + h] + path[eA * 8 + h];
        float dpB = dist[eB * 8 + h] + path[eB * 8 + h];
        float pA = qA.x * kv.x + qA.y * kv.y;
        float pB = qB.x * kv.x + qB.y * kv.y;
        pA += __shfl_xor(pA, 1); pA += __shfl_xor(pA, 2); pA += __shfl_xor(pA, 4);
        pB += __shfl_xor(pB, 1); pB += __shfl_xor(pB, 2); pB += __shfl_xor(pB, 4);
        pA += dpA; pB += dpB;

        float mn = fmaxf(m, pA);
        float c  = __expf(m - mn);
        float w  = __expf(pA - mn);
        sden = sden * c + w;
        ax = ax * c + w * vA.x;
        ay = ay * c + w * vA.y;
        m = mn;

        mn = fmaxf(m, pB);
        c  = __expf(m - mn);
        w  = __expf(pB - mn);
        sden = sden * c + w;
        ax = ax * c + w * vB.x;
        ay = ay * c + w * vB.y;
        m = mn;
    }
    if (i < end) {                           // tail edge
        int sA = ssrc[i];
        int eA = eidx[i];
        float2 qA = *(const float2*)(qb + (size_t)sA * D + 2 * lane);
        float2 vA = *(const float2*)(vb + (size_t)sA * D + 2 * lane);
        float dpA = dist[eA * 8 + h] + path[eA * 8 + h];
        float pA = qA.x * kv.x + qA.y * kv.y;
        pA += __shfl_xor(pA, 1); pA += __shfl_xor(pA, 2); pA += __shfl_xor(pA, 4);
        pA += dpA;
        float mn = fmaxf(m, pA);
        float c  = __expf(m - mn);
        float w  = __expf(pA - mn);
        sden = sden * c + w;
        ax = ax * c + w * vA.x;
        ay = ay * c + w * vA.y;
    }

    float2 r = make_float2(0.f, 0.f);
    if (end > beg) {
        float inv = 1.f / sden;
        r = make_float2(ax * inv, ay * inv);
    }
    *(float2*)(agg + (size_t)node * D + 2 * lane) = r;
}

// ---------------------------------------------------------------------------
// K5: out = node_feature + agg @ W_out.T + b_out
// 64 nodes/block, 2 col-tiles of 64. as[64][132]+ws[64][130] = 67KB
// -> 2 blocks/CU. Conflict-free float2 W reads as in K1.
// ---------------------------------------------------------------------------
__launch_bounds__(256)
__global__ void k_out(const float* __restrict__ agg, const float* __restrict__ Wout,
                      const float* __restrict__ bout, const float* __restrict__ nf,
                      float* __restrict__ out) {
    __shared__ float as_[64][132];
    __shared__ float ws[64][130];
    const int tid = threadIdx.x;
    const int n0 = blockIdx.x * 64;

    for (int i = tid; i < 64 * 32; i += 256) {
        int node = i >> 5, off = (i & 31) << 2;
        float4 w = make_float4(0.f, 0.f, 0.f, 0.f);
        if (n0 + node < N_NODES)
            w = *(const float4*)(agg + (size_t)(n0 + node) * D + off);
        *(float4*)&as_[node][off] = w;
    }

    const int tc = tid & 31, tn = tid >> 5;   // nodes tn*8..tn*8+7

    for (int ct = 0; ct < 2; ct++) {
        if (ct) __syncthreads();
        for (int i = tid; i < 64 * 32; i += 256) {
            int r = i >> 5, off = (i & 31) << 2;
            float4 w = *(const float4*)(Wout + (size_t)(ct * 64 + r) * D + off);
            *(float2*)&ws[r][off]     = make_float2(w.x, w.y);
            *(float2*)&ws[r][off + 2] = make_float2(w.z, w.w);
        }
        __syncthreads();   // also covers as_ staging on ct==0

        float acc[8][2];
        #pragma unroll
        for (int a = 0; a < 8; a++)
            #pragma unroll
            for (int b = 0; b < 2; b++) acc[a][b] = 0.f;

        #pragma unroll 2
        for (int k4 = 0; k4 < 32; k4++) {
            float2 wa[2], wb[2];
            #pragma unroll
            for (int b = 0; b < 2; b++) {
                wa[b] = *(const float2*)&ws[tc + 32 * b][k4 * 4];
                wb[b] = *(const float2*)&ws[tc + 32 * b][k4 * 4 + 2];
            }
            #pragma unroll
            for (int a = 0; a < 8; a++) {
                float4 xv = *(const float4*)&as_[tn * 8 + a][k4 * 4];  // broadcast
                #pragma unroll
                for (int b = 0; b < 2; b++) {
                    acc[a][b] += xv.x * wa[b].x + xv.y * wa[b].y +
                                 xv.z * wb[b].x + xv.w * wb[b].y;
                }
            }
        }

        #pragma unroll
        for (int b = 0; b < 2; b++) {
            int c = ct * 64 + tc + 32 * b;
            float bias = bout[c];
            #pragma unroll
            for (int a = 0; a < 8; a++) {
                int node = n0 + tn * 8 + a;
                if (node >= N_NODES) continue;
                out[(size_t)node * D + c] = nf[(size_t)node * D + c] + bias + acc[a][b];
            }
        }
    }
}

// ---------------------------------------------------------------------------
// launch
// ---------------------------------------------------------------------------
extern "C" void kernel_launch(void* const* d_in, const int* in_sizes, int n_in,
                              void* d_out, int out_size, void* d_ws, size_t ws_size,
                              hipStream_t stream) {
    const float* nf    = (const float*)d_in[0];
    const float* dist  = (const float*)d_in[1];
    const float* path  = (const float*)d_in[2];
    const float* gamma = (const float*)d_in[3];
    const float* beta  = (const float*)d_in[4];
    const float* Wqkv  = (const float*)d_in[5];
    const float* bqkv  = (const float*)d_in[6];
    const float* Wout  = (const float*)d_in[7];
    const float* bout  = (const float*)d_in[8];
    const int*   src   = (const int*)d_in[9];
    const int*   dst   = (const int*)d_in[10];
    float* out = (float*)d_out;

    // workspace layout: 4 x N*128 floats + CSR ints (~109.5 MB total)
    float* qb  = (float*)d_ws;
    float* kb  = qb + (size_t)N_NODES * D;
    float* vb  = kb + (size_t)N_NODES * D;
    float* agg = vb + (size_t)N_NODES * D;
    int* ssrc      = (int*)(agg + (size_t)N_NODES * D);   // N_EDGES
    int* eidx      = ssrc + N_EDGES;                      // N_EDGES
    int* cnt       = eidx + N_EDGES;                      // N_NODES
    int* ptrs      = cnt + N_NODES;                       // N_NODES
    int* row_start = ptrs + N_NODES;                      // N_NODES + 1

    (void)in_sizes; (void)n_in; (void)out_size; (void)ws_size;

    hipLaunchKernelGGL(k_zero, dim3((N_NODES + 255) / 256), dim3(256), 0, stream, cnt);
    hipLaunchKernelGGL(k_hist, dim3((N_EDGES + 255) / 256), dim3(256), 0, stream,
                       dst, cnt);
    hipLaunchKernelGGL(k_scan, dim3(1), dim3(SCAN_T), 0, stream,
                       cnt, row_start, ptrs);
    hipLaunchKernelGGL(k_fill, dim3((N_EDGES + 255) / 256), dim3(256), 0, stream,
                       src, dst, ptrs, ssrc, eidx);

    hipLaunchKernelGGL(k_ln_qkv, dim3((N_NODES + 31) / 32), dim3(256), 0, stream,
                       nf, gamma, beta, Wqkv, bqkv, qb, kb, vb);

    hipLaunchKernelGGL(k_gather, dim3((N_NODES + 3) / 4), dim3(256), 0, stream,
                       qb, kb, vb, dist, path, row_start, ssrc, eidx, agg);

    hipLaunchKernelGGL(k_out, dim3((N_NODES + 63) / 64), dim3(256), 0, stream,
                       agg, Wout, bout, nf, out);
}